// Round 1
// baseline (24365.158 us; speedup 1.0000x reference)
//
#include <hip/hip_runtime.h>
#include <hip/hip_cooperative_groups.h>

namespace cg = cooperative_groups;

// ============================================================================
// ENAS RNN scan + decode for MI355X (gfx950).  Round 4: fused cooperative scan.
//
// Round-3 analysis: 384 serial per-level kernel launches dominate (avg ~20 µs
// per level vs ~3-6 µs of real work).  This round fuses the whole T=64 scan
// into ONE cooperative kernel with grid.sync() between DAG levels.  Cross-XCD
// visibility of h hi/lo slots is enforced with explicit agent-scope fences
// (release before sync = L2 writeback, acquire after = L2/L1 invalidate),
// replicating what kernel boundaries used to provide.  Math is bit-identical
// to round 3.  Fallback to the multi-launch path if coop launch fails.
//
// MFMA 16x16x32 bf16 layouts (m89-verified):
//   A: lane holds A[m=lane&15][k=(lane>>4)*8 + j], j=0..7
//   B: lane holds B[k=(lane>>4)*8+j][n=lane&15]
//   C/D: col = lane&15, row = (lane>>4)*4 + reg
// ============================================================================

#define TPB 256

#define Tt 64
#define Bb 64
#define Hh 1000
#define Ee 1000
#define Vv 10000
#define HP 1024                 // padded row stride for h buffers
#define SLOT (Bb * HP)          // elems per h slot
#define KW 2000                 // E + H (w_x* row length)
#define NTILE 63                // ceil(1000/16)

typedef unsigned short u16;
typedef short bf16x8 __attribute__((ext_vector_type(8)));
typedef float f32x4 __attribute__((ext_vector_type(4)));

// ---- ws layout (bytes) ----
#define OFF_HLO   1572864u     // hhi: 12*SLOT*2
#define OFF_C0    3145728u     // hlo: 12*SLOT*2
#define OFF_OBF   3407872u     // c0 : 64*HP*4
#define OFF_WC    11796480u    // obf: 4096*HP*2 (bf16 outputs for decode A)
#define WC_WXH    0u           // bf16 w_xh  : 2e6*2 = 4,000,000
#define WC_WXC    4000000u     // bf16 w_xc  : 4,000,000
#define WC_WH     8000000u     // bf16 Wh    : 22,000,000
#define WC_WCC    30000000u    // bf16 Wc    : 22,000,000
#define WC_END    52000000u
#define WS_CACHED (OFF_WC + WC_END)   // 63,796,480

// outb (fp32 leaf sums, 4096*1024*4 = 16,777,216 B) lives at the start of
// d_out (163.8 MB fp32 output); consumed by cvt before decode writes d_out.
#define OUTB_BYTES 16777216u

__device__ __forceinline__ float bf2f(u16 u) {
  union { unsigned int i; float f; } c; c.i = ((unsigned int)u) << 16; return c.f;
}
__device__ __forceinline__ u16 f2bf(float f) {
  union { float f; unsigned int i; } c; c.f = f;
  unsigned int u = c.i + 0x7FFFu + ((c.i >> 16) & 1u);
  return (u16)(u >> 16);
}
// Sanitize: clamp to +-16, maps NaN -> -16 (fmaxf/fminf return non-NaN arg).
__device__ __forceinline__ float sanf(float x) {
  return fminf(fmaxf(x, -16.0f), 16.0f);
}
__device__ __forceinline__ f32x4 mfma16(bf16x8 a, bf16x8 b, f32x4 c) {
  return __builtin_amdgcn_mfma_f32_16x16x32_bf16(a, b, c, 0, 0, 0);
}
__device__ __forceinline__ bf16x8 ld8(const u16* p) { return *(const bf16x8*)p; }
__device__ __forceinline__ bf16x8 cvt8(const float* p) {
  float4 v0 = *(const float4*)p, v1 = *(const float4*)(p + 4);
  bf16x8 r;
  r[0] = (short)f2bf(sanf(v0.x)); r[1] = (short)f2bf(sanf(v0.y));
  r[2] = (short)f2bf(sanf(v0.z)); r[3] = (short)f2bf(sanf(v0.w));
  r[4] = (short)f2bf(sanf(v1.x)); r[5] = (short)f2bf(sanf(v1.y));
  r[6] = (short)f2bf(sanf(v1.z)); r[7] = (short)f2bf(sanf(v1.w));
  return r;
}
// B-fragment load: cached bf16 (ws) or in-register f32->bf16. Element offset.
template<bool CB>
__device__ __forceinline__ bf16x8 ldB(const void* base, size_t off) {
  if constexpr (CB) return *(const bf16x8*)((const u16*)base + off);
  else              return cvt8((const float*)base + off);
}

__device__ __forceinline__ float sigm(float x) { return 1.0f / (1.0f + __expf(-x)); }
__device__ __forceinline__ float tanh_(float x) {
  float e = __expf(-2.0f * fabsf(x));
  float t = (1.0f - e) / (1.0f + e);
  return x < 0.0f ? -t : t;
}
__device__ __forceinline__ float actf(int a, float x) {
  if (a == 0) return fmaxf(x, 0.0f);   // relu
  if (a == 1) return tanh_(x);         // tanh
  if (a == 2) return sigm(x);          // sigmoid
  return x;                            // identity
}

// Edge schedule, grouped by DAG level (positions 0..10).
// act: 0=relu 1=tanh 2=sigmoid 3=identity
__constant__ short g_e[11]    = {0, 1, 2, 3, 10, 4, 5, 6, 7, 8, 9};
__constant__ short g_src[11]  = {0, 0, 1, 1, 6, 2, 2, 3, 3, 4, 4};
__constant__ short g_dst[11]  = {1, 6, 2, 8, 7, 3, 9, 4, 10, 5, 11};
__constant__ short g_act[11]  = {0, 1, 0, 2, 1, 1, 0, 3, 1, 0, 2};
__constant__ short g_leaf[11] = {0, 0, 0, 1, 1, 0, 1, 0, 1, 1, 1};

// f32 -> sanitized bf16 (weight cache). n divisible by 4.
__global__ void __launch_bounds__(TPB) wcvt_kernel(const float* __restrict__ src,
                                                   u16* __restrict__ dst, int n) {
  int i = (blockIdx.x * TPB + threadIdx.x) * 4;
  if (i < n) {
    float4 v = *(const float4*)(src + i);
    dst[i + 0] = f2bf(sanf(v.x));
    dst[i + 1] = f2bf(sanf(v.y));
    dst[i + 2] = f2bf(sanf(v.z));
    dst[i + 3] = f2bf(sanf(v.w));
  }
}

// hidden [64,1000] f32 -> h slot 11 hi/lo (pads already zeroed by memset).
__global__ void __launch_bounds__(TPB) stage_kernel(const float* __restrict__ hidden,
                                                    u16* __restrict__ hhi,
                                                    u16* __restrict__ hlo) {
  int b = blockIdx.x;
  for (int k = threadIdx.x; k < Hh; k += TPB) {
    float x = sanf(hidden[b * Hh + k]);
    u16 h = f2bf(x);
    hhi[11 * SLOT + b * HP + k] = h;
    hlo[11 * SLOT + b * HP + k] = f2bf(x - bf2f(h));
  }
}

// ---------------------------------------------------------------------------
// Per-level work bodies (shared by the fused coop kernel and the fallback
// multi-launch kernels).
// ---------------------------------------------------------------------------

template<bool CB>
__device__ __forceinline__ void lev0_body(
    const int bid, const int t,
    const int* __restrict__ inputs, const float* __restrict__ emb,
    const void* __restrict__ wxh, const float* __restrict__ bxh,
    const void* __restrict__ wxc, const float* __restrict__ bxc,
    u16* __restrict__ hhi, u16* __restrict__ hlo, float* __restrict__ c0b)
{
  const int tid = threadIdx.x;
  const int lane = tid & 63, wave = tid >> 6;
  const int l15 = lane & 15, quad = lane >> 4;
  const int koff = quad * 8;

  const int n0 = bid * 16;                      // 63 tiles
  const int nrow = n0 + l15;
  const int ncl = nrow < Hh ? nrow : Hh - 1;
  const size_t wrow = (size_t)ncl * KW;
  const int mrow = wave * 16 + l15;
  int ix = inputs[t * Bb + mrow];
  ix = ix < 0 ? 0 : (ix >= Vv ? Vv - 1 : ix);   // defensive clamp
  const float* px = emb + (size_t)ix * Ee;
  const u16* phh = hhi + 11 * SLOT + (size_t)mrow * HP;
  const u16* phl = hlo + 11 * SLOT + (size_t)mrow * HP;

  f32x4 ac = {0.f, 0.f, 0.f, 0.f}, ah = {0.f, 0.f, 0.f, 0.f};
  // phase 1: x part (k 0..999), A converted f32->bf16 in-register
  #pragma unroll 2
  for (int c = 0; c < 31; ++c) {
    int k = c * 32 + koff;
    bf16x8 a = cvt8(px + k);
    ac = mfma16(a, ldB<CB>(wxc, wrow + k), ac);
    ah = mfma16(a, ldB<CB>(wxh, wrow + k), ah);
  }
  { // tail: mask A (embedding row end); B row len 2000 -> in-bounds
    int k = 992 + koff;
    bf16x8 a = {0, 0, 0, 0, 0, 0, 0, 0};
    if (quad == 0) a = cvt8(px + k);
    ac = mfma16(a, ldB<CB>(wxc, wrow + k), ac);
    ah = mfma16(a, ldB<CB>(wxh, wrow + k), ah);
  }
  // phase 2: h_prev part (hi + lo), B cols 1000..1999
  #pragma unroll 2
  for (int c = 0; c < 31; ++c) {
    int k = c * 32 + koff;
    bf16x8 a0 = ld8(phh + k), a1 = ld8(phl + k);
    bf16x8 b0 = ldB<CB>(wxc, wrow + 1000 + k), b1 = ldB<CB>(wxh, wrow + 1000 + k);
    ac = mfma16(a0, b0, ac); ac = mfma16(a1, b0, ac);
    ah = mfma16(a0, b1, ah); ah = mfma16(a1, b1, ah);
  }
  { // tail: A reads zeroed pad (safe); mask B (w_x* row end)
    int k = 992 + koff;
    bf16x8 a0 = ld8(phh + k), a1 = ld8(phl + k);
    bf16x8 b0 = {0, 0, 0, 0, 0, 0, 0, 0}, b1 = {0, 0, 0, 0, 0, 0, 0, 0};
    if (quad == 0) { b0 = ldB<CB>(wxc, wrow + 1000 + k); b1 = ldB<CB>(wxh, wrow + 1000 + k); }
    ac = mfma16(a0, b0, ac); ac = mfma16(a1, b0, ac);
    ah = mfma16(a0, b1, ah); ah = mfma16(a1, b1, ah);
  }
  const int ne = n0 + l15;
  if (ne < Hh) {
    float bxcv = sanf(bxc[ne]), bxhv = sanf(bxh[ne]);
    #pragma unroll
    for (int r = 0; r < 4; ++r) {
      int me = wave * 16 + quad * 4 + r;
      size_t idx = (size_t)me * HP + ne;
      float c0v = sigm(ac[r] + bxcv);
      float hp = bf2f(hhi[11 * SLOT + idx]) + bf2f(hlo[11 * SLOT + idx]);
      float h0 = sanf(c0v * tanh_(ah[r] + bxhv) + (1.0f - c0v) * hp);
      c0b[idx] = c0v;
      u16 hb = f2bf(h0);
      hhi[idx] = hb;                      // slot 0
      hlo[idx] = f2bf(h0 - bf2f(hb));
    }
  }
}

template<bool CB>
__device__ __forceinline__ void edge_body(
    const int bid, const int e0, const int t,
    const void* __restrict__ Wh, const void* __restrict__ Wc,
    u16* __restrict__ hhi, u16* __restrict__ hlo,
    const float* __restrict__ c0b, float* __restrict__ outb)
{
  const int tid = threadIdx.x;
  const int lane = tid & 63, wave = tid >> 6;
  const int l15 = lane & 15, quad = lane >> 4;
  const int koff = quad * 8;

  const int er = bid / NTILE;
  const int e = e0 + er;
  const int n0 = (bid - er * NTILE) * 16;
  const int we = g_e[e], src = g_src[e], dst = g_dst[e];
  const int nrow = n0 + l15;
  const int ncl = nrow < Hh ? nrow : Hh - 1;
  const size_t wrow = (size_t)we * (Hh * Hh) + (size_t)ncl * Hh;
  const int mrow = wave * 16 + l15;
  const u16* pah = hhi + (size_t)src * SLOT + (size_t)mrow * HP;
  const u16* pal = hlo + (size_t)src * SLOT + (size_t)mrow * HP;

  f32x4 ac = {0.f, 0.f, 0.f, 0.f}, ah = {0.f, 0.f, 0.f, 0.f};
  #pragma unroll 2
  for (int c = 0; c < 31; ++c) {
    int k = c * 32 + koff;
    bf16x8 a0 = ld8(pah + k), a1 = ld8(pal + k);
    bf16x8 b0 = ldB<CB>(Wc, wrow + k), b1 = ldB<CB>(Wh, wrow + k);
    ac = mfma16(a0, b0, ac); ac = mfma16(a1, b0, ac);
    ah = mfma16(a0, b1, ah); ah = mfma16(a1, b1, ah);
  }
  { // tail: A reads zeroed pad (safe); mask B (row end)
    int k = 992 + koff;
    bf16x8 a0 = ld8(pah + k), a1 = ld8(pal + k);
    bf16x8 b0 = {0, 0, 0, 0, 0, 0, 0, 0}, b1 = {0, 0, 0, 0, 0, 0, 0, 0};
    if (quad == 0) { b0 = ldB<CB>(Wc, wrow + k); b1 = ldB<CB>(Wh, wrow + k); }
    ac = mfma16(a0, b0, ac); ac = mfma16(a1, b0, ac);
    ah = mfma16(a0, b1, ah); ah = mfma16(a1, b1, ah);
  }
  const int ne = n0 + l15;
  if (ne < Hh) {
    const int act = g_act[e], leaf = g_leaf[e];
    const u16* pih = hhi + (size_t)src * SLOT;
    const u16* pil = hlo + (size_t)src * SLOT;
    u16* pjh = hhi + (size_t)dst * SLOT;
    u16* pjl = hlo + (size_t)dst * SLOT;
    #pragma unroll
    for (int r = 0; r < 4; ++r) {
      int me = wave * 16 + quad * 4 + r;
      size_t idx = (size_t)me * HP + ne;
      float cj = sigm(ac[r]);
      float av = actf(act, ah[r]);
      float hi_v = bf2f(pih[idx]) + bf2f(pil[idx]);
      float hj = sanf(cj * av + (1.0f - c0b[idx]) * hi_v);  // blend uses c0 (!)
      u16 hb = f2bf(hj);
      pjh[idx] = hb;
      pjl[idx] = f2bf(hj - bf2f(hb));
      if (leaf) atomicAdd(outb + (size_t)(t * Bb + me) * HP + ne, hj);
    }
  }
}

// ---------------------------------------------------------------------------
// Fused cooperative scan: all 64 timesteps, grid.sync() between DAG levels.
// Grid = 3*NTILE = 189 blocks (max tiles in any level).  Explicit agent-scope
// fences around each sync make h-slot writes visible across XCDs (per-XCD L2
// is not coherent; release = wbl2, acquire = inv).
// ---------------------------------------------------------------------------
template<bool CB>
__global__ void __launch_bounds__(TPB, 1) scan_fused(
    const int* __restrict__ inputs, const float* __restrict__ emb,
    const void* __restrict__ wxh, const float* __restrict__ bxh,
    const void* __restrict__ wxc, const float* __restrict__ bxc,
    const void* __restrict__ Wh, const void* __restrict__ Wc,
    u16* __restrict__ hhi, u16* __restrict__ hlo,
    float* __restrict__ c0b, float* __restrict__ outb)
{
  cg::grid_group grid = cg::this_grid();
  const int bid = blockIdx.x;

  constexpr int LOFF[5] = {0, 2, 5, 7, 9};
  constexpr int LCNT[5] = {2, 3, 2, 2, 2};

  for (int t = 0; t < Tt; ++t) {
    if (bid < NTILE)
      lev0_body<CB>(bid, t, inputs, emb, wxh, bxh, wxc, bxc, hhi, hlo, c0b);
    __builtin_amdgcn_fence(__ATOMIC_RELEASE, "agent");
    grid.sync();
    __builtin_amdgcn_fence(__ATOMIC_ACQUIRE, "agent");

    #pragma unroll
    for (int lev = 0; lev < 5; ++lev) {
      if (bid < LCNT[lev] * NTILE)
        edge_body<CB>(bid, LOFF[lev], t, Wh, Wc, hhi, hlo, c0b, outb);
      __builtin_amdgcn_fence(__ATOMIC_RELEASE, "agent");
      grid.sync();
      __builtin_amdgcn_fence(__ATOMIC_ACQUIRE, "agent");
    }
  }
}

// ---------------------------------------------------------------------------
// Fallback multi-launch kernels (round-3 behavior) in case the cooperative
// launch is rejected by the runtime.
// ---------------------------------------------------------------------------
template<bool CB>
__global__ void __launch_bounds__(TPB) lev0_kernel(
    int t, const int* __restrict__ inputs, const float* __restrict__ emb,
    const void* __restrict__ wxh, const float* __restrict__ bxh,
    const void* __restrict__ wxc, const float* __restrict__ bxc,
    u16* __restrict__ hhi, u16* __restrict__ hlo, float* __restrict__ c0b)
{
  lev0_body<CB>(blockIdx.x, t, inputs, emb, wxh, bxh, wxc, bxc, hhi, hlo, c0b);
}

template<bool CB>
__global__ void __launch_bounds__(TPB) edge_kernel(
    int e0, int t, const void* __restrict__ Wh, const void* __restrict__ Wc,
    u16* __restrict__ hhi, u16* __restrict__ hlo,
    const float* __restrict__ c0b, float* __restrict__ outb)
{
  edge_body<CB>(blockIdx.x, e0, t, Wh, Wc, hhi, hlo, c0b, outb);
}

// fp32 leaf sums (in d_out) -> bf16 * (1/6) into ws.obf; pads stay zero.
__global__ void __launch_bounds__(TPB) cvt_kernel(const float* __restrict__ outb,
                                                  u16* __restrict__ obf) {
  size_t i = ((size_t)blockIdx.x * TPB + threadIdx.x) * 4;
  float4 v = *(const float4*)(outb + i);
  const float s = 1.0f / 6.0f;
  obf[i + 0] = f2bf(sanf(v.x * s));
  obf[i + 1] = f2bf(sanf(v.y * s));
  obf[i + 2] = f2bf(sanf(v.z * s));
  obf[i + 3] = f2bf(sanf(v.w * s));
}

// decoded[4096,10000] = out @ dec_w.T + dec_b, f32 out. 64x64 tile per WG.
__global__ void __launch_bounds__(TPB) decode_kernel(
    const u16* __restrict__ obf, const float* __restrict__ decw,
    const float* __restrict__ decb, float* __restrict__ out)
{
  const int tid = threadIdx.x;
  const int lane = tid & 63, wave = tid >> 6;
  const int l15 = lane & 15, quad = lane >> 4;
  const int bm = blockIdx.x % 64;   // consecutive blocks share bn -> B reuse in L2
  const int bn = blockIdx.x / 64;
  const int mrow = bm * 64 + wave * 16 + l15;
  const u16* pa = obf + (size_t)mrow * HP;
  const float* pb[4];
  #pragma unroll
  for (int j = 0; j < 4; ++j) {
    int v = bn * 64 + j * 16 + l15;
    if (v > Vv - 1) v = Vv - 1;
    pb[j] = decw + (size_t)v * Hh;
  }
  f32x4 acc[4];
  #pragma unroll
  for (int j = 0; j < 4; ++j) acc[j] = (f32x4){0.f, 0.f, 0.f, 0.f};
  const int koff = quad * 8;
  #pragma unroll 2
  for (int c = 0; c < 31; ++c) {
    int k = c * 32 + koff;
    bf16x8 a = ld8(pa + k);
    #pragma unroll
    for (int j = 0; j < 4; ++j) acc[j] = mfma16(a, cvt8(pb[j] + k), acc[j]);
  }
  { // tail: A covers zeroed pads (in-bounds); mask B (dec_w row end)
    int k = 992 + koff;
    bf16x8 a = ld8(pa + k);
    bf16x8 z = {0, 0, 0, 0, 0, 0, 0, 0};
    #pragma unroll
    for (int j = 0; j < 4; ++j) {
      bf16x8 b = z;
      if (quad == 0) b = cvt8(pb[j] + k);
      acc[j] = mfma16(a, b, acc[j]);
    }
  }
  #pragma unroll
  for (int j = 0; j < 4; ++j) {
    int ne = bn * 64 + j * 16 + l15;
    if (ne < Vv) {
      float bv = sanf(decb[ne]);
      #pragma unroll
      for (int r = 0; r < 4; ++r) {
        int me = bm * 64 + wave * 16 + quad * 4 + r;
        out[(size_t)me * Vv + ne] = acc[j][r] + bv;
      }
    }
  }
}

extern "C" void kernel_launch(void* const* d_in, const int* in_sizes, int n_in,
                              void* d_out, int out_size, void* d_ws, size_t ws_size,
                              hipStream_t stream) {
  const int*   inputs = (const int*)d_in[0];
  const float* hidden = (const float*)d_in[1];
  const float* emb    = (const float*)d_in[2];
  const float* wxh    = (const float*)d_in[3];
  const float* bxh    = (const float*)d_in[4];
  const float* wxc    = (const float*)d_in[5];
  const float* bxc    = (const float*)d_in[6];
  const float* Wh     = (const float*)d_in[7];
  const float* Wc     = (const float*)d_in[8];
  const float* decw   = (const float*)d_in[9];
  const float* decb   = (const float*)d_in[10];

  char* ws = (char*)d_ws;
  u16*   hhi = (u16*)(ws);
  u16*   hlo = (u16*)(ws + OFF_HLO);
  float* c0b = (float*)(ws + OFF_C0);
  u16*   obf = (u16*)(ws + OFF_OBF);
  float* outb = (float*)d_out;            // fp32 leaf sums, consumed before decode

  const bool cached = (ws_size >= (size_t)WS_CACHED);
  u16* wxhb = (u16*)(ws + OFF_WC + WC_WXH);
  u16* wxcb = (u16*)(ws + OFF_WC + WC_WXC);
  u16* Whb  = (u16*)(ws + OFF_WC + WC_WH);
  u16* Wcb  = (u16*)(ws + OFF_WC + WC_WCC);

  // zero h hi/lo (pads must be 0) + c0, and the leaf-sum region of d_out
  hipMemsetAsync(ws, 0, OFF_OBF, stream);
  hipMemsetAsync(d_out, 0, OUTB_BYTES, stream);

  if (cached) {
    wcvt_kernel<<<(2000000 / 4 + TPB - 1) / TPB, TPB, 0, stream>>>(wxh, wxhb, 2000000);
    wcvt_kernel<<<(2000000 / 4 + TPB - 1) / TPB, TPB, 0, stream>>>(wxc, wxcb, 2000000);
    wcvt_kernel<<<(11000000 / 4 + TPB - 1) / TPB, TPB, 0, stream>>>(Wh, Whb, 11000000);
    wcvt_kernel<<<(11000000 / 4 + TPB - 1) / TPB, TPB, 0, stream>>>(Wc, Wcb, 11000000);
  }
  stage_kernel<<<Bb, TPB, 0, stream>>>(hidden, hhi, hlo);

  // ---- fused cooperative scan (one kernel for all 64 timesteps) ----
  const void* a_wxh = cached ? (const void*)wxhb : (const void*)wxh;
  const void* a_wxc = cached ? (const void*)wxcb : (const void*)wxc;
  const void* a_Wh  = cached ? (const void*)Whb  : (const void*)Wh;
  const void* a_Wc  = cached ? (const void*)Wcb  : (const void*)Wc;
  void* ka[12] = {(void*)&inputs, (void*)&emb, (void*)&a_wxh, (void*)&bxh,
                  (void*)&a_wxc, (void*)&bxc, (void*)&a_Wh, (void*)&a_Wc,
                  (void*)&hhi, (void*)&hlo, (void*)&c0b, (void*)&outb};
  dim3 sgrid(3 * NTILE), sblk(TPB);
  hipError_t ce = cached
    ? hipLaunchCooperativeKernel(scan_fused<true>,  sgrid, sblk, ka, 0, stream)
    : hipLaunchCooperativeKernel(scan_fused<false>, sgrid, sblk, ka, 0, stream);

  if (ce != hipSuccess) {
    (void)hipGetLastError();   // clear sticky error; fall back to multi-launch
    static const int lev_off[5] = {0, 2, 5, 7, 9};
    static const int lev_cnt[5] = {2, 3, 2, 2, 2};
    for (int t = 0; t < Tt; ++t) {
      if (cached) {
        lev0_kernel<true><<<NTILE, TPB, 0, stream>>>(t, inputs, emb, wxhb, bxh,
                                                     wxcb, bxc, hhi, hlo, c0b);
        for (int lev = 0; lev < 5; ++lev)
          edge_kernel<true><<<lev_cnt[lev] * NTILE, TPB, 0, stream>>>(
              lev_off[lev], t, Whb, Wcb, hhi, hlo, c0b, outb);
      } else {
        lev0_kernel<false><<<NTILE, TPB, 0, stream>>>(t, inputs, emb, wxh, bxh,
                                                      wxc, bxc, hhi, hlo, c0b);
        for (int lev = 0; lev < 5; ++lev)
          edge_kernel<false><<<lev_cnt[lev] * NTILE, TPB, 0, stream>>>(
              lev_off[lev], t, Wh, Wc, hhi, hlo, c0b, outb);
      }
    }
  }

  cvt_kernel<<<(Tt * Bb * HP) / (TPB * 4), TPB, 0, stream>>>(outb, obf);
  decode_kernel<<<64 * 157, TPB, 0, stream>>>(obf, decw, decb, (float*)d_out);
}

// Round 2
// 6943.102 us; speedup vs baseline: 3.5093x; 3.5093x over previous
//
#include <hip/hip_runtime.h>

// ============================================================================
// ENAS RNN scan + decode for MI355X (gfx950).  Round 5: multi-launch + split-K.
//
// Round-4 post-mortem: cooperative fusion regressed 3x (grid.sync + agent
// fences = full L2 writeback/invalidate per level at 4-waves/CU occupancy ->
// 60us/level).  Reverted to multi-launch (kernel boundary is the cheaper
// device-wide sync).
//
// Round-5 theory: each of the 384 serial stages is fetch-LATENCY-bound:
// ~4-8 MB of weights re-fetched past an invalidated L2 by only ~500 waves
// with ~8 outstanding loads each.  Fix: split-K x4 inside each block
// (1024 threads = 16 waves = 4 kchunks x 4 mquads), partial f32 accums
// reduced through 32 KB of LDS, epilogue by the kc==0 waves.  4x waves and
// 4x independent weight streams per stage; math identical up to f32
// reassociation.
//
// MFMA 16x16x32 bf16 layouts (m89-verified):
//   A: lane holds A[m=lane&15][k=(lane>>4)*8 + j], j=0..7
//   B: lane holds B[k=(lane>>4)*8+j][n=lane&15]
//   C/D: col = lane&15, row = (lane>>4)*4 + reg
// ============================================================================

#define TPB 256            // helper kernels
#define STPB 1024          // scan kernels: 16 waves

#define Tt 64
#define Bb 64
#define Hh 1000
#define Ee 1000
#define Vv 10000
#define HP 1024                 // padded row stride for h buffers
#define SLOT (Bb * HP)          // elems per h slot
#define KW 2000                 // E + H (w_x* row length)
#define NTILE 63                // ceil(1000/16)

typedef unsigned short u16;
typedef short bf16x8 __attribute__((ext_vector_type(8)));
typedef float f32x4 __attribute__((ext_vector_type(4)));

// ---- ws layout (bytes) ----
#define OFF_HLO   1572864u     // hhi: 12*SLOT*2
#define OFF_C0    3145728u     // hlo: 12*SLOT*2
#define OFF_OBF   3407872u     // c0 : 64*HP*4
#define OFF_WC    11796480u    // obf: 4096*HP*2 (bf16 outputs for decode A)
#define WC_WXH    0u           // bf16 w_xh  : 2e6*2 = 4,000,000
#define WC_WXC    4000000u     // bf16 w_xc  : 4,000,000
#define WC_WH     8000000u     // bf16 Wh    : 22,000,000
#define WC_WCC    30000000u    // bf16 Wc    : 22,000,000
#define WC_END    52000000u
#define WS_CACHED (OFF_WC + WC_END)   // 63,796,480

// outb (fp32 leaf sums, 4096*1024*4 = 16,777,216 B) lives at the start of
// d_out (163.8 MB fp32 output); consumed by cvt before decode writes d_out.
#define OUTB_BYTES 16777216u

__device__ __forceinline__ float bf2f(u16 u) {
  union { unsigned int i; float f; } c; c.i = ((unsigned int)u) << 16; return c.f;
}
__device__ __forceinline__ u16 f2bf(float f) {
  union { float f; unsigned int i; } c; c.f = f;
  unsigned int u = c.i + 0x7FFFu + ((c.i >> 16) & 1u);
  return (u16)(u >> 16);
}
// Sanitize: clamp to +-16, maps NaN -> -16 (fmaxf/fminf return non-NaN arg).
__device__ __forceinline__ float sanf(float x) {
  return fminf(fmaxf(x, -16.0f), 16.0f);
}
__device__ __forceinline__ f32x4 mfma16(bf16x8 a, bf16x8 b, f32x4 c) {
  return __builtin_amdgcn_mfma_f32_16x16x32_bf16(a, b, c, 0, 0, 0);
}
__device__ __forceinline__ bf16x8 ld8(const u16* p) { return *(const bf16x8*)p; }
__device__ __forceinline__ bf16x8 cvt8(const float* p) {
  float4 v0 = *(const float4*)p, v1 = *(const float4*)(p + 4);
  bf16x8 r;
  r[0] = (short)f2bf(sanf(v0.x)); r[1] = (short)f2bf(sanf(v0.y));
  r[2] = (short)f2bf(sanf(v0.z)); r[3] = (short)f2bf(sanf(v0.w));
  r[4] = (short)f2bf(sanf(v1.x)); r[5] = (short)f2bf(sanf(v1.y));
  r[6] = (short)f2bf(sanf(v1.z)); r[7] = (short)f2bf(sanf(v1.w));
  return r;
}
// B-fragment load: cached bf16 (ws) or in-register f32->bf16. Element offset.
template<bool CB>
__device__ __forceinline__ bf16x8 ldB(const void* base, size_t off) {
  if constexpr (CB) return *(const bf16x8*)((const u16*)base + off);
  else              return cvt8((const float*)base + off);
}

__device__ __forceinline__ float sigm(float x) { return 1.0f / (1.0f + __expf(-x)); }
__device__ __forceinline__ float tanh_(float x) {
  float e = __expf(-2.0f * fabsf(x));
  float t = (1.0f - e) / (1.0f + e);
  return x < 0.0f ? -t : t;
}
__device__ __forceinline__ float actf(int a, float x) {
  if (a == 0) return fmaxf(x, 0.0f);   // relu
  if (a == 1) return tanh_(x);         // tanh
  if (a == 2) return sigm(x);          // sigmoid
  return x;                            // identity
}

// Edge schedule, grouped by DAG level (positions 0..10).
// act: 0=relu 1=tanh 2=sigmoid 3=identity
__constant__ short g_e[11]    = {0, 1, 2, 3, 10, 4, 5, 6, 7, 8, 9};
__constant__ short g_src[11]  = {0, 0, 1, 1, 6, 2, 2, 3, 3, 4, 4};
__constant__ short g_dst[11]  = {1, 6, 2, 8, 7, 3, 9, 4, 10, 5, 11};
__constant__ short g_act[11]  = {0, 1, 0, 2, 1, 1, 0, 3, 1, 0, 2};
__constant__ short g_leaf[11] = {0, 0, 0, 1, 1, 0, 1, 0, 1, 1, 1};

// f32 -> sanitized bf16 (weight cache). n divisible by 4.
__global__ void __launch_bounds__(TPB) wcvt_kernel(const float* __restrict__ src,
                                                   u16* __restrict__ dst, int n) {
  int i = (blockIdx.x * TPB + threadIdx.x) * 4;
  if (i < n) {
    float4 v = *(const float4*)(src + i);
    dst[i + 0] = f2bf(sanf(v.x));
    dst[i + 1] = f2bf(sanf(v.y));
    dst[i + 2] = f2bf(sanf(v.z));
    dst[i + 3] = f2bf(sanf(v.w));
  }
}

// hidden [64,1000] f32 -> h slot 11 hi/lo (pads already zeroed by memset).
__global__ void __launch_bounds__(TPB) stage_kernel(const float* __restrict__ hidden,
                                                    u16* __restrict__ hhi,
                                                    u16* __restrict__ hlo) {
  int b = blockIdx.x;
  for (int k = threadIdx.x; k < Hh; k += TPB) {
    float x = sanf(hidden[b * Hh + k]);
    u16 h = f2bf(x);
    hhi[11 * SLOT + b * HP + k] = h;
    hlo[11 * SLOT + b * HP + k] = f2bf(x - bf2f(h));
  }
}

// ---------------------------------------------------------------------------
// lev0: x/h cell.  1024 threads = 16 waves = kc (K-chunk, 4) x mquad (m, 4).
// Each wave does c-iters [kc*8, kc*8+8) (kc3: ..31 + tail) of BOTH phases,
// then LDS reduction across kc, epilogue by kc==0 waves.
// ---------------------------------------------------------------------------
template<bool CB>
__global__ void __launch_bounds__(STPB) lev0_kernel(
    int t, const int* __restrict__ inputs, const float* __restrict__ emb,
    const void* __restrict__ wxh, const float* __restrict__ bxh,
    const void* __restrict__ wxc, const float* __restrict__ bxc,
    u16* __restrict__ hhi, u16* __restrict__ hlo, float* __restrict__ c0b)
{
  __shared__ float red[16][8][64];      // 32 KB: [wave][acc-reg][lane]
  const int tid = threadIdx.x;
  const int lane = tid & 63, wave = tid >> 6;
  const int mquad = wave & 3, kc = wave >> 2;
  const int l15 = lane & 15, quad = lane >> 4;
  const int koff = quad * 8;

  const int n0 = blockIdx.x * 16;               // 63 blocks
  const int nrow = n0 + l15;
  const int ncl = nrow < Hh ? nrow : Hh - 1;
  const size_t wrow = (size_t)ncl * KW;
  const int mrow = mquad * 16 + l15;
  int ix = inputs[t * Bb + mrow];
  ix = ix < 0 ? 0 : (ix >= Vv ? Vv - 1 : ix);   // defensive clamp
  const float* px = emb + (size_t)ix * Ee;
  const u16* phh = hhi + 11 * SLOT + (size_t)mrow * HP;
  const u16* phl = hlo + 11 * SLOT + (size_t)mrow * HP;

  const int cb = kc * 8;
  const int ce = (kc == 3) ? 31 : cb + 8;

  f32x4 ac = {0.f, 0.f, 0.f, 0.f}, ah = {0.f, 0.f, 0.f, 0.f};
  // phase 1: x part (k 0..999), A converted f32->bf16 in-register
  #pragma unroll 2
  for (int c = cb; c < ce; ++c) {
    int k = c * 32 + koff;
    bf16x8 a = cvt8(px + k);
    ac = mfma16(a, ldB<CB>(wxc, wrow + k), ac);
    ah = mfma16(a, ldB<CB>(wxh, wrow + k), ah);
  }
  if (kc == 3) { // tail: mask A (embedding row end); B row len 2000 -> in-bounds
    int k = 992 + koff;
    bf16x8 a = {0, 0, 0, 0, 0, 0, 0, 0};
    if (quad == 0) a = cvt8(px + k);
    ac = mfma16(a, ldB<CB>(wxc, wrow + k), ac);
    ah = mfma16(a, ldB<CB>(wxh, wrow + k), ah);
  }
  // phase 2: h_prev part (hi + lo), B cols 1000..1999
  #pragma unroll 2
  for (int c = cb; c < ce; ++c) {
    int k = c * 32 + koff;
    bf16x8 a0 = ld8(phh + k), a1 = ld8(phl + k);
    bf16x8 b0 = ldB<CB>(wxc, wrow + 1000 + k), b1 = ldB<CB>(wxh, wrow + 1000 + k);
    ac = mfma16(a0, b0, ac); ac = mfma16(a1, b0, ac);
    ah = mfma16(a0, b1, ah); ah = mfma16(a1, b1, ah);
  }
  if (kc == 3) { // tail: A reads zeroed pad (safe); mask B (w_x* row end)
    int k = 992 + koff;
    bf16x8 a0 = ld8(phh + k), a1 = ld8(phl + k);
    bf16x8 b0 = {0, 0, 0, 0, 0, 0, 0, 0}, b1 = {0, 0, 0, 0, 0, 0, 0, 0};
    if (quad == 0) { b0 = ldB<CB>(wxc, wrow + 1000 + k); b1 = ldB<CB>(wxh, wrow + 1000 + k); }
    ac = mfma16(a0, b0, ac); ac = mfma16(a1, b0, ac);
    ah = mfma16(a0, b1, ah); ah = mfma16(a1, b1, ah);
  }

  // split-K reduction through LDS
  #pragma unroll
  for (int r = 0; r < 4; ++r) {
    red[wave][r][lane]     = ac[r];
    red[wave][4 + r][lane] = ah[r];
  }
  __syncthreads();
  if (kc == 0) {
    #pragma unroll
    for (int p = 1; p < 4; ++p) {
      const int w2 = p * 4 + mquad;
      #pragma unroll
      for (int r = 0; r < 4; ++r) {
        ac[r] += red[w2][r][lane];
        ah[r] += red[w2][4 + r][lane];
      }
    }
    const int ne = n0 + l15;
    if (ne < Hh) {
      float bxcv = sanf(bxc[ne]), bxhv = sanf(bxh[ne]);
      #pragma unroll
      for (int r = 0; r < 4; ++r) {
        int me = mquad * 16 + quad * 4 + r;
        size_t idx = (size_t)me * HP + ne;
        float c0v = sigm(ac[r] + bxcv);
        float hp = bf2f(hhi[11 * SLOT + idx]) + bf2f(hlo[11 * SLOT + idx]);
        float h0 = sanf(c0v * tanh_(ah[r] + bxhv) + (1.0f - c0v) * hp);
        c0b[idx] = c0v;
        u16 hb = f2bf(h0);
        hhi[idx] = hb;                      // slot 0
        hlo[idx] = f2bf(h0 - bf2f(hb));
      }
    }
  }
}

// ---------------------------------------------------------------------------
// edge level: same 16-wave split-K structure.
// ---------------------------------------------------------------------------
template<bool CB>
__global__ void __launch_bounds__(STPB) edge_kernel(
    int e0, int t, const void* __restrict__ Wh, const void* __restrict__ Wc,
    u16* __restrict__ hhi, u16* __restrict__ hlo,
    const float* __restrict__ c0b, float* __restrict__ outb)
{
  __shared__ float red[16][8][64];      // 32 KB
  const int tid = threadIdx.x;
  const int lane = tid & 63, wave = tid >> 6;
  const int mquad = wave & 3, kc = wave >> 2;
  const int l15 = lane & 15, quad = lane >> 4;
  const int koff = quad * 8;

  const int er = blockIdx.x / NTILE;
  const int e = e0 + er;
  const int n0 = (blockIdx.x - er * NTILE) * 16;
  const int we = g_e[e], src = g_src[e], dst = g_dst[e];
  const int nrow = n0 + l15;
  const int ncl = nrow < Hh ? nrow : Hh - 1;
  const size_t wrow = (size_t)we * (Hh * Hh) + (size_t)ncl * Hh;
  const int mrow = mquad * 16 + l15;
  const u16* pah = hhi + (size_t)src * SLOT + (size_t)mrow * HP;
  const u16* pal = hlo + (size_t)src * SLOT + (size_t)mrow * HP;

  const int cb = kc * 8;
  const int ce = (kc == 3) ? 31 : cb + 8;

  f32x4 ac = {0.f, 0.f, 0.f, 0.f}, ah = {0.f, 0.f, 0.f, 0.f};
  #pragma unroll 2
  for (int c = cb; c < ce; ++c) {
    int k = c * 32 + koff;
    bf16x8 a0 = ld8(pah + k), a1 = ld8(pal + k);
    bf16x8 b0 = ldB<CB>(Wc, wrow + k), b1 = ldB<CB>(Wh, wrow + k);
    ac = mfma16(a0, b0, ac); ac = mfma16(a1, b0, ac);
    ah = mfma16(a0, b1, ah); ah = mfma16(a1, b1, ah);
  }
  if (kc == 3) { // tail: A reads zeroed pad (safe); mask B (row end)
    int k = 992 + koff;
    bf16x8 a0 = ld8(pah + k), a1 = ld8(pal + k);
    bf16x8 b0 = {0, 0, 0, 0, 0, 0, 0, 0}, b1 = {0, 0, 0, 0, 0, 0, 0, 0};
    if (quad == 0) { b0 = ldB<CB>(Wc, wrow + k); b1 = ldB<CB>(Wh, wrow + k); }
    ac = mfma16(a0, b0, ac); ac = mfma16(a1, b0, ac);
    ah = mfma16(a0, b1, ah); ah = mfma16(a1, b1, ah);
  }

  // split-K reduction through LDS
  #pragma unroll
  for (int r = 0; r < 4; ++r) {
    red[wave][r][lane]     = ac[r];
    red[wave][4 + r][lane] = ah[r];
  }
  __syncthreads();
  if (kc == 0) {
    #pragma unroll
    for (int p = 1; p < 4; ++p) {
      const int w2 = p * 4 + mquad;
      #pragma unroll
      for (int r = 0; r < 4; ++r) {
        ac[r] += red[w2][r][lane];
        ah[r] += red[w2][4 + r][lane];
      }
    }
    const int ne = n0 + l15;
    if (ne < Hh) {
      const int act = g_act[e], leaf = g_leaf[e];
      const u16* pih = hhi + (size_t)src * SLOT;
      const u16* pil = hlo + (size_t)src * SLOT;
      u16* pjh = hhi + (size_t)dst * SLOT;
      u16* pjl = hlo + (size_t)dst * SLOT;
      #pragma unroll
      for (int r = 0; r < 4; ++r) {
        int me = mquad * 16 + quad * 4 + r;
        size_t idx = (size_t)me * HP + ne;
        float cj = sigm(ac[r]);
        float av = actf(act, ah[r]);
        float hi_v = bf2f(pih[idx]) + bf2f(pil[idx]);
        float hj = sanf(cj * av + (1.0f - c0b[idx]) * hi_v);  // blend uses c0 (!)
        u16 hb = f2bf(hj);
        pjh[idx] = hb;
        pjl[idx] = f2bf(hj - bf2f(hb));
        if (leaf) atomicAdd(outb + (size_t)(t * Bb + me) * HP + ne, hj);
      }
    }
  }
}

// fp32 leaf sums (in d_out) -> bf16 * (1/6) into ws.obf; pads stay zero.
__global__ void __launch_bounds__(TPB) cvt_kernel(const float* __restrict__ outb,
                                                  u16* __restrict__ obf) {
  size_t i = ((size_t)blockIdx.x * TPB + threadIdx.x) * 4;
  float4 v = *(const float4*)(outb + i);
  const float s = 1.0f / 6.0f;
  obf[i + 0] = f2bf(sanf(v.x * s));
  obf[i + 1] = f2bf(sanf(v.y * s));
  obf[i + 2] = f2bf(sanf(v.z * s));
  obf[i + 3] = f2bf(sanf(v.w * s));
}

// decoded[4096,10000] = out @ dec_w.T + dec_b, f32 out. 64x64 tile per WG.
__global__ void __launch_bounds__(TPB) decode_kernel(
    const u16* __restrict__ obf, const float* __restrict__ decw,
    const float* __restrict__ decb, float* __restrict__ out)
{
  const int tid = threadIdx.x;
  const int lane = tid & 63, wave = tid >> 6;
  const int l15 = lane & 15, quad = lane >> 4;
  const int bm = blockIdx.x % 64;   // consecutive blocks share bn -> B reuse in L2
  const int bn = blockIdx.x / 64;
  const int mrow = bm * 64 + wave * 16 + l15;
  const u16* pa = obf + (size_t)mrow * HP;
  const float* pb[4];
  #pragma unroll
  for (int j = 0; j < 4; ++j) {
    int v = bn * 64 + j * 16 + l15;
    if (v > Vv - 1) v = Vv - 1;
    pb[j] = decw + (size_t)v * Hh;
  }
  f32x4 acc[4];
  #pragma unroll
  for (int j = 0; j < 4; ++j) acc[j] = (f32x4){0.f, 0.f, 0.f, 0.f};
  const int koff = quad * 8;
  #pragma unroll 2
  for (int c = 0; c < 31; ++c) {
    int k = c * 32 + koff;
    bf16x8 a = ld8(pa + k);
    #pragma unroll
    for (int j = 0; j < 4; ++j) acc[j] = mfma16(a, cvt8(pb[j] + k), acc[j]);
  }
  { // tail: A covers zeroed pads (in-bounds); mask B (dec_w row end)
    int k = 992 + koff;
    bf16x8 a = ld8(pa + k);
    bf16x8 z = {0, 0, 0, 0, 0, 0, 0, 0};
    #pragma unroll
    for (int j = 0; j < 4; ++j) {
      bf16x8 b = z;
      if (quad == 0) b = cvt8(pb[j] + k);
      acc[j] = mfma16(a, b, acc[j]);
    }
  }
  #pragma unroll
  for (int j = 0; j < 4; ++j) {
    int ne = bn * 64 + j * 16 + l15;
    if (ne < Vv) {
      float bv = sanf(decb[ne]);
      #pragma unroll
      for (int r = 0; r < 4; ++r) {
        int me = bm * 64 + wave * 16 + quad * 4 + r;
        out[(size_t)me * Vv + ne] = acc[j][r] + bv;
      }
    }
  }
}

extern "C" void kernel_launch(void* const* d_in, const int* in_sizes, int n_in,
                              void* d_out, int out_size, void* d_ws, size_t ws_size,
                              hipStream_t stream) {
  const int*   inputs = (const int*)d_in[0];
  const float* hidden = (const float*)d_in[1];
  const float* emb    = (const float*)d_in[2];
  const float* wxh    = (const float*)d_in[3];
  const float* bxh    = (const float*)d_in[4];
  const float* wxc    = (const float*)d_in[5];
  const float* bxc    = (const float*)d_in[6];
  const float* Wh     = (const float*)d_in[7];
  const float* Wc     = (const float*)d_in[8];
  const float* decw   = (const float*)d_in[9];
  const float* decb   = (const float*)d_in[10];

  char* ws = (char*)d_ws;
  u16*   hhi = (u16*)(ws);
  u16*   hlo = (u16*)(ws + OFF_HLO);
  float* c0b = (float*)(ws + OFF_C0);
  u16*   obf = (u16*)(ws + OFF_OBF);
  float* outb = (float*)d_out;            // fp32 leaf sums, consumed before decode

  const bool cached = (ws_size >= (size_t)WS_CACHED);
  u16* wxhb = (u16*)(ws + OFF_WC + WC_WXH);
  u16* wxcb = (u16*)(ws + OFF_WC + WC_WXC);
  u16* Whb  = (u16*)(ws + OFF_WC + WC_WH);
  u16* Wcb  = (u16*)(ws + OFF_WC + WC_WCC);

  // zero h hi/lo (pads must be 0) + c0, and the leaf-sum region of d_out
  hipMemsetAsync(ws, 0, OFF_OBF, stream);
  hipMemsetAsync(d_out, 0, OUTB_BYTES, stream);

  if (cached) {
    wcvt_kernel<<<(2000000 / 4 + TPB - 1) / TPB, TPB, 0, stream>>>(wxh, wxhb, 2000000);
    wcvt_kernel<<<(2000000 / 4 + TPB - 1) / TPB, TPB, 0, stream>>>(wxc, wxcb, 2000000);
    wcvt_kernel<<<(11000000 / 4 + TPB - 1) / TPB, TPB, 0, stream>>>(Wh, Whb, 11000000);
    wcvt_kernel<<<(11000000 / 4 + TPB - 1) / TPB, TPB, 0, stream>>>(Wc, Wcb, 11000000);
  }
  stage_kernel<<<Bb, TPB, 0, stream>>>(hidden, hhi, hlo);

  // levels: scheduled positions {0..1},{2..4},{5..6},{7..8},{9..10}
  static const int lev_off[5] = {0, 2, 5, 7, 9};
  static const int lev_cnt[5] = {2, 3, 2, 2, 2};

  for (int t = 0; t < Tt; ++t) {
    if (cached) {
      lev0_kernel<true><<<NTILE, STPB, 0, stream>>>(t, inputs, emb, wxhb, bxh,
                                                    wxcb, bxc, hhi, hlo, c0b);
      for (int lev = 0; lev < 5; ++lev)
        edge_kernel<true><<<lev_cnt[lev] * NTILE, STPB, 0, stream>>>(
            lev_off[lev], t, Whb, Wcb, hhi, hlo, c0b, outb);
    } else {
      lev0_kernel<false><<<NTILE, STPB, 0, stream>>>(t, inputs, emb, wxh, bxh,
                                                     wxc, bxc, hhi, hlo, c0b);
      for (int lev = 0; lev < 5; ++lev)
        edge_kernel<false><<<lev_cnt[lev] * NTILE, STPB, 0, stream>>>(
            lev_off[lev], t, Wh, Wc, hhi, hlo, c0b, outb);
    }
  }

  cvt_kernel<<<(Tt * Bb * HP) / (TPB * 4), TPB, 0, stream>>>(outb, obf);
  decode_kernel<<<64 * 157, TPB, 0, stream>>>(obf, decw, decb, (float*)d_out);
}